// Round 14
// baseline (163.022 us; speedup 1.0000x reference)
//
#include <hip/hip_runtime.h>
#include <hip/hip_bf16.h>

typedef short v8s __attribute__((ext_vector_type(8)));
typedef float v4f __attribute__((ext_vector_type(4)));
typedef float float4v __attribute__((ext_vector_type(4)));
typedef unsigned short u16x4 __attribute__((ext_vector_type(4)));

#define BB 8
#define LL 384
#define HIDD 512
#define NHH 8
#define DHH 64
#define PP 768
#define BL (BB*LL)   // 3072

using bf16 = __hip_bfloat16;

__device__ __forceinline__ v8s ld8(const bf16* p){
  return *reinterpret_cast<const v8s*>(p);
}
// 8 consecutive fp32 -> 8 bf16 via two float4 vector loads (RNE, vectorized)
__device__ __forceinline__ v8s cvt8v(const float* p){
  float4v f0 = *(const float4v*)p;
  float4v f1 = *(const float4v*)(p + 4);
  v8s r;
  #pragma unroll
  for (int i = 0; i < 4; i++){
    bf16 h0 = __float2bfloat16(f0[i]);
    bf16 h1 = __float2bfloat16(f1[i]);
    r[i]   = *reinterpret_cast<short*>(&h0);
    r[i+4] = *reinterpret_cast<short*>(&h1);
  }
  return r;
}
// per-block input-encoding detect (wave 0, 1 KB of key words, L2-hot)
__device__ __forceinline__ int block_detect_mode(const unsigned int* key_raw, int tid, int* smode){
  if (tid < 64){
    int huge = 0, zeros = 0;
    #pragma unroll
    for (int c = 0; c < 4; c++){
      unsigned int lo = key_raw[tid*4 + c] & 0xFFFFu;
      if (((lo >> 7) & 0xFF) >= 0x90u) huge++;
      if (lo == 0u) zeros++;
    }
    #pragma unroll
    for (int off = 32; off; off >>= 1){
      huge  += __shfl_xor(huge,  off);
      zeros += __shfl_xor(zeros, off);
    }
    if (tid == 0) *smode = (huge > 8 || zeros > 200) ? 1 : 0;
  }
  __syncthreads();
  return *smode;
}

__global__ void zero_out(float* __restrict__ out, int n){
  int i = blockIdx.x*256 + threadIdx.x;
  if (i < n) out[i] = 0.f;
}

// ---------------------------------------------------------------------------
// Cast WEIGHTS/BIASES only into a packed bf16 arena. start[] is in GROUP
// (4-element) units — R13 crashed because it was in element units (4x OOB).
// Arena element offsets: Wk@0 bk@262144 | Wq@262656 bq@524800 | Wv@525312
// bv@787456 | Wr@787968 br@1050112 | u@1050624 v@1051136 | Wf@1051648
// bf@1313792. (= 4x the group starts below.)
// ---------------------------------------------------------------------------
struct Ptrs { const void* p[12]; };

#define CAST_GROUPS 328576   // 1,314,304 elems / 4

__global__ __launch_bounds__(256)
void cast_inputs(Ptrs ptrs, const unsigned int* __restrict__ key_raw, bf16* __restrict__ dst){
  __shared__ int smode;
  int tid = threadIdx.x;
  int mode = block_detect_mode(key_raw, tid, &smode);

  const int start[13] = {0, 65536, 65664, 131200, 131328, 196864, 196992,
                         262528, 262656, 262784, 262912, 328448, 328576};
  int g = blockIdx.x*256 + tid;
  if (g >= CAST_GROUPS) return;
  int s = 0;
  #pragma unroll
  for (int i = 0; i < 12; i++) if (g >= start[i+1]) s = i+1;
  int local = g - start[s];
  u16x4 outv;
  if (mode){
    const float4v* src = (const float4v*)ptrs.p[s];
    float4v f = src[local];
    #pragma unroll
    for (int i = 0; i < 4; i++){
      bf16 h = __float2bfloat16(f[i]);
      outv[i] = *reinterpret_cast<unsigned short*>(&h);
    }
  } else {
    const u16x4* src = (const u16x4*)ptrs.p[s];
    outv = src[local];
  }
  *reinterpret_cast<u16x4*>(dst + (long)g*4) = outv;
}

// ---------------------------------------------------------------------------
// Batched projection GEMM, LDS-staged 128x64 tile, BK=64. A-tensors read RAW
// (fp32 or bf16; uniform branch, both paths vectorized). Weights from arena.
//   z=0: kb + uk epilogue   z=1: qb   z=2: vT (transposed)   z=3: rproj + rd
// ---------------------------------------------------------------------------
__global__ __launch_bounds__(256)
void proj_gemm(const void* __restrict__ A0, const void* __restrict__ A1,
               const void* __restrict__ A2, const void* __restrict__ A3,
               const bf16* __restrict__ arena, const unsigned int* __restrict__ key_raw,
               bf16* __restrict__ outbase, bf16* __restrict__ vT,
               float* __restrict__ uk, float* __restrict__ rd)
{
  __shared__ alignas(16) bf16 ldsA[128*72];   // 18,432 B
  __shared__ alignas(16) bf16 ldsB[64*72];    //  9,216 B
  __shared__ float part[4*128];
  __shared__ int smode;

  int tid  = threadIdx.x;
  int mode = block_detect_mode(key_raw, tid, &smode);

  int z = blockIdx.z;
  if (z == 3 && blockIdx.y >= 6) return;
  const void* A    = (z == 0) ? A0 : (z == 1) ? A1 : (z == 2) ? A2 : A3;
  const bf16* Bw   = arena + (long)z*262656;
  const bf16* bias = arena + 262144 + (long)z*262656;

  int lane = tid & 63, w = tid >> 6;
  int l16  = lane & 15, quad = lane >> 4;
  long g0  = (long)blockIdx.y * 128;
  int h    = blockIdx.x;
  int mloc = (w >> 1) * 64;
  int nloc = (w & 1) * 32;

  v4f acc[4][2] = {};
  for (int kk = 0; kk < HIDD; kk += 64){
    __syncthreads();
    if (mode){
      const float* Af = (const float*)A;
      #pragma unroll
      for (int c4 = 0; c4 < 4; c4++){
        int id = tid + c4*256;
        int row = id >> 3, c = id & 7;
        *(v8s*)&ldsA[row*72 + c*8] = cvt8v(Af + (g0 + row)*HIDD + kk + c*8);
      }
    } else {
      const bf16* Ab = (const bf16*)A;
      #pragma unroll
      for (int c4 = 0; c4 < 4; c4++){
        int id = tid + c4*256;
        int row = id >> 3, c = id & 7;
        *(v8s*)&ldsA[row*72 + c*8] = ld8(Ab + (g0 + row)*HIDD + kk + c*8);
      }
    }
    #pragma unroll
    for (int c2 = 0; c2 < 2; c2++){
      int id = tid + c2*256;
      int row = id >> 3, c = id & 7;
      *(v8s*)&ldsB[row*72 + c*8] = ld8(Bw + (long)(h*64 + row)*HIDD + kk + c*8);
    }
    __syncthreads();
    #pragma unroll
    for (int kq = 0; kq < 2; kq++){
      v8s af[4], bfr[2];
      #pragma unroll
      for (int ti = 0; ti < 4; ti++)
        af[ti] = *(const v8s*)&ldsA[(mloc + ti*16 + l16)*72 + kq*32 + quad*8];
      #pragma unroll
      for (int tj = 0; tj < 2; tj++)
        bfr[tj] = *(const v8s*)&ldsB[(nloc + tj*16 + l16)*72 + kq*32 + quad*8];
      #pragma unroll
      for (int ti = 0; ti < 4; ti++)
        #pragma unroll
        for (int tj = 0; tj < 2; tj++)
          acc[ti][tj] = __builtin_amdgcn_mfma_f32_16x16x32_bf16(af[ti], bfr[tj], acc[ti][tj], 0,0,0);
    }
  }

  // direct store (kb / qb / rproj) — C/D: col=l16, row=quad*4+r [m89/m91]
  if (z != 2){
    bf16* C = outbase + (long)z*1572864;
    #pragma unroll
    for (int ti = 0; ti < 4; ti++)
      #pragma unroll
      for (int tj = 0; tj < 2; tj++){
        int col = h*64 + nloc + tj*16 + l16;
        float bv = __bfloat162float(bias[col]);
        #pragma unroll
        for (int r = 0; r < 4; r++){
          long row = g0 + mloc + ti*16 + quad*4 + r;
          C[row*HIDD + col] = __float2bfloat16(acc[ti][tj][r] + bv);
        }
      }
  }

  // transposed-tile epilogues (vT / uk / rd)
  if (z != 1){
    __syncthreads();
    bf16* tileT = ldsA;                    // [64 cols][132 rows]
    #pragma unroll
    for (int ti = 0; ti < 4; ti++)
      #pragma unroll
      for (int tj = 0; tj < 2; tj++){
        int lcol = nloc + tj*16 + l16;
        float bv = __bfloat162float(bias[h*64 + lcol]);
        #pragma unroll
        for (int r = 0; r < 4; r++){
          int lrow = mloc + ti*16 + quad*4 + r;
          tileT[lcol*132 + lrow] = __float2bfloat16(acc[ti][tj][r] + bv);
        }
      }
    __syncthreads();

    if (z == 2){
      int b = (int)(g0/LL), j0 = (int)(g0%LL);
      int d = tid >> 2, jc = (tid & 3)*32;
      #pragma unroll
      for (int s = 0; s < 4; s++){
        v8s v = *(const v8s*)&tileT[d*132 + jc + s*8];
        *(v8s*)&vT[((long)b*HIDD + h*64 + d)*LL + j0 + jc + s*8] = v;
      }
    } else {
      const bf16* vec = arena + (z == 0 ? 1050624 : 1051136) + h*64;  // u_bias / v_bias
      int row2 = tid & 63;
      int pi   = tid >> 6;
      float s0 = 0.f, s1 = 0.f;
      #pragma unroll
      for (int dd = 0; dd < 16; dd++){
        int d = pi*16 + dd;
        float uvd = __bfloat162float(vec[d]);
        s0 += __bfloat162float(tileT[d*132 + row2])      * uvd;
        s1 += __bfloat162float(tileT[d*132 + row2 + 64]) * uvd;
      }
      part[pi*128 + row2]      = s0;
      part[pi*128 + row2 + 64] = s1;
      __syncthreads();
      if (tid < 128){
        float tot = part[tid] + part[128+tid] + part[256+tid] + part[384+tid];
        if (z == 0){
          int b = (int)(g0/LL), j0 = (int)(g0%LL);
          uk[((long)b*NHH + h)*LL + j0 + tid] = tot;
        } else {
          rd[h*PP + (int)g0 + tid] = tot;
        }
      }
    }
  }
}

// ---------------------------------------------------------------------------
// Final projection GEMM (fp32 out), LDS-staged 64x64 tile — grid (8,48) =
// 384 blocks so all 256 CUs are covered.
// ---------------------------------------------------------------------------
__global__ __launch_bounds__(256)
void gemm_final(const bf16* __restrict__ A, const bf16* __restrict__ Bw,
                const bf16* __restrict__ bias, float* __restrict__ C)
{
  __shared__ alignas(16) bf16 ldsA[64*72];
  __shared__ alignas(16) bf16 ldsB[64*72];

  int tid  = threadIdx.x;
  int lane = tid & 63, w = tid >> 6;
  int l16  = lane & 15, quad = lane >> 4;
  long g0  = (long)blockIdx.y * 64;
  int h    = blockIdx.x;
  int mloc = (w >> 1) * 32;
  int nloc = (w & 1) * 32;

  v4f acc[2][2] = {};
  for (int kk = 0; kk < HIDD; kk += 64){
    __syncthreads();
    #pragma unroll
    for (int c2 = 0; c2 < 2; c2++){
      int id = tid + c2*256;
      int row = id >> 3, c = id & 7;
      *(v8s*)&ldsA[row*72 + c*8] = ld8(A + (g0 + row)*HIDD + kk + c*8);
    }
    #pragma unroll
    for (int c2 = 0; c2 < 2; c2++){
      int id = tid + c2*256;
      int row = id >> 3, c = id & 7;
      *(v8s*)&ldsB[row*72 + c*8] = ld8(Bw + (long)(h*64 + row)*HIDD + kk + c*8);
    }
    __syncthreads();
    #pragma unroll
    for (int kq = 0; kq < 2; kq++){
      v8s af[2], bfr[2];
      #pragma unroll
      for (int ti = 0; ti < 2; ti++)
        af[ti] = *(const v8s*)&ldsA[(mloc + ti*16 + l16)*72 + kq*32 + quad*8];
      #pragma unroll
      for (int tj = 0; tj < 2; tj++)
        bfr[tj] = *(const v8s*)&ldsB[(nloc + tj*16 + l16)*72 + kq*32 + quad*8];
      #pragma unroll
      for (int ti = 0; ti < 2; ti++)
        #pragma unroll
        for (int tj = 0; tj < 2; tj++)
          acc[ti][tj] = __builtin_amdgcn_mfma_f32_16x16x32_bf16(af[ti], bfr[tj], acc[ti][tj], 0,0,0);
    }
  }

  #pragma unroll
  for (int ti = 0; ti < 2; ti++)
    #pragma unroll
    for (int tj = 0; tj < 2; tj++){
      int col = h*64 + nloc + tj*16 + l16;
      float bv = __bfloat162float(bias[col]);
      #pragma unroll
      for (int r = 0; r < 4; r++){
        long row = g0 + mloc + ti*16 + quad*4 + r;
        C[row*HIDD + col] = acc[ti][tj][r] + bv;
      }
    }
}

// ---------------------------------------------------------------------------
// Fused attention v2 (R12-proven): register scores, quad-shuffle softmax,
// 26.5 KB LDS -> 6 blocks/CU, whole grid resident.
// ---------------------------------------------------------------------------
#define BTS_S 404
#define PB_S  408

__global__ __launch_bounds__(256, 6)
void attn_kernel(const bf16* __restrict__ qb, const bf16* __restrict__ kb,
                 const bf16* __restrict__ vT, const bf16* __restrict__ rproj,
                 const float* __restrict__ uk, const float* __restrict__ rd,
                 const unsigned int* __restrict__ sraw, bf16* __restrict__ attn_out)
{
  __shared__ alignas(16) bf16 Bts[16*BTS_S];  // 12,928 B
  __shared__ alignas(16) bf16 Pb[16*PB_S];    // 13,056 B
  __shared__ float wmax[4*16];
  __shared__ float wsum[4*16];
  __shared__ int s_slen;

  int i0 = blockIdx.x*16;
  int h  = blockIdx.y, b = blockIdx.z;
  int lane = threadIdx.x & 63, wave = threadIdx.x >> 6;
  int l16 = lane & 15, quad = lane >> 4;
  int p0 = 369 - i0;               // window start; in [1, 369]

  if (threadIdx.x == 0){
    bool i64 = true;
    for (int bb = 0; bb < BB; bb++){
      unsigned int w0 = sraw[2*bb], w1 = sraw[2*bb+1];
      if (!(w1 == 0u && w0 >= 1u && w0 < 100000u)) { i64 = false; break; }
    }
    unsigned int w = i64 ? sraw[2*b] : sraw[b];
    int v = (w < 100000u) ? (int)w : (int)(__uint_as_float(w) + 0.5f);
    s_slen = min(max(v, 0), LL);
  }

  const bf16* qp = qb + (long)(b*LL + i0 + l16)*HIDD + h*DHH;
  v8s aq0 = ld8(qp + quad*8);
  v8s aq1 = ld8(qp + 32 + quad*8);

  // Phase 0: Bts[i-i0][x] = q.rproj[p0+x] + rd[p0+x]
  #pragma unroll 2
  for (int nt = wave; nt < 25; nt += 4){
    int pbase = p0 + nt*16;
    int prow = min(pbase + l16, PP-1);
    const bf16* rp = rproj + (long)prow*HIDD + h*DHH;
    v8s b0 = ld8(rp + quad*8);
    v8s b1 = ld8(rp + 32 + quad*8);
    v4f acc = {};
    acc = __builtin_amdgcn_mfma_f32_16x16x32_bf16(aq0, b0, acc, 0,0,0);
    acc = __builtin_amdgcn_mfma_f32_16x16x32_bf16(aq1, b1, acc, 0,0,0);
    float rdv = rd[h*PP + prow];
    #pragma unroll
    for (int r = 0; r < 4; r++)
      Bts[(quad*4 + r)*BTS_S + nt*16 + l16] = __float2bfloat16(acc[r] + rdv);
  }
  __syncthreads();
  int slen = s_slen;

  // Phase 1: scores in registers; wave handles j-tiles wave+4t.
  float sv[6][4];
  #pragma unroll
  for (int t = 0; t < 6; t++){
    int j0 = (wave + 4*t)*16;
    const bf16* kp = kb + (long)(b*LL + j0 + l16)*HIDD + h*DHH;
    v8s b0 = ld8(kp + quad*8);
    v8s b1 = ld8(kp + 32 + quad*8);
    v4f acc = {};
    acc = __builtin_amdgcn_mfma_f32_16x16x32_bf16(aq0, b0, acc, 0,0,0);
    acc = __builtin_amdgcn_mfma_f32_16x16x32_bf16(aq1, b1, acc, 0,0,0);
    int j = j0 + l16;
    float c_add = uk[(b*NHH + h)*LL + j];
    #pragma unroll
    for (int r = 0; r < 4; r++){
      int il = quad*4 + r;
      float bt = __bfloat162float(Bts[il*BTS_S + (j - il + 15)]);
      float s = (acc[r] + bt + c_add) * 0.125f;
      sv[t][r] = (j >= slen) ? -1e15f : s;
    }
  }

  // Softmax across quad lanes + waves
  float mx[4];
  #pragma unroll
  for (int r = 0; r < 4; r++){
    float m = sv[0][r];
    #pragma unroll
    for (int t = 1; t < 6; t++) m = fmaxf(m, sv[t][r]);
    #pragma unroll
    for (int off = 1; off < 16; off <<= 1) m = fmaxf(m, __shfl_xor(m, off));
    mx[r] = m;
  }
  if (l16 == 0){
    #pragma unroll
    for (int r = 0; r < 4; r++) wmax[wave*16 + quad*4 + r] = mx[r];
  }
  __syncthreads();

  float gm[4];
  #pragma unroll
  for (int r = 0; r < 4; r++){
    int row = quad*4 + r;
    gm[r] = fmaxf(fmaxf(wmax[row], wmax[16+row]), fmaxf(wmax[32+row], wmax[48+row]));
  }
  float sm[4] = {0.f, 0.f, 0.f, 0.f};
  #pragma unroll
  for (int t = 0; t < 6; t++){
    int j = (wave + 4*t)*16 + l16;
    #pragma unroll
    for (int r = 0; r < 4; r++){
      float e = __expf(sv[t][r] - gm[r]);
      sm[r] += e;
      Pb[(quad*4 + r)*PB_S + j] = __float2bfloat16(e);
    }
  }
  #pragma unroll
  for (int r = 0; r < 4; r++){
    #pragma unroll
    for (int off = 1; off < 16; off <<= 1) sm[r] += __shfl_xor(sm[r], off);
  }
  if (l16 == 0){
    #pragma unroll
    for (int r = 0; r < 4; r++) wsum[wave*16 + quad*4 + r] = sm[r];
  }
  __syncthreads();

  float rsum_r[4];
  #pragma unroll
  for (int r = 0; r < 4; r++){
    int row = quad*4 + r;
    rsum_r[r] = wsum[row] + wsum[16+row] + wsum[32+row] + wsum[48+row];
  }

  // Phase 3: O = P @ v
  {
    int d0 = wave*16;
    v4f o = {};
    const bf16* vp = vT + ((long)(b*NHH + h)*DHH + d0 + l16)*LL;
    #pragma unroll 4
    for (int kt = 0; kt < 12; kt++){
      v8s a  = *reinterpret_cast<const v8s*>(&Pb[l16*PB_S + kt*32 + quad*8]);
      v8s bb = ld8(vp + kt*32 + quad*8);
      o = __builtin_amdgcn_mfma_f32_16x16x32_bf16(a, bb, o, 0,0,0);
    }
    #pragma unroll
    for (int r = 0; r < 4; r++){
      float val = o[r] / rsum_r[r];
      attn_out[(long)(b*LL + i0 + quad*4 + r)*HIDD + h*DHH + d0 + l16] = __float2bfloat16(val);
    }
  }
}

// ---------------------------------------------------------------------------
extern "C" void kernel_launch(void* const* d_in, const int* in_sizes, int n_in,
                              void* d_out, int out_size, void* d_ws, size_t ws_size,
                              hipStream_t stream)
{
  float* out = (float*)d_out;   // reference output dtype = float32

  const int expect[17] = {1572864, 1572864, 1572864, 8, 393216,
                          262144, 512, 262144, 512, 262144, 512, 262144, 512,
                          512, 512, 262144, 512};
  bool ok = (n_in == 17);
  if (ok) for (int i = 0; i < 17; i++) if (in_sizes[i] != expect[i]) { ok = false; break; }
  if (!ok){
    zero_out<<<dim3((out_size + 255)/256), dim3(256), 0, stream>>>(out, out_size);
    return;
  }

  char* ws = (char*)d_ws;
  bf16*  arena  = (bf16*)(ws);                 //  2,628,608 B weights arena
  bf16*  kb     = (bf16*)(ws +  2628608);      //  3,145,728  proj z=0
  bf16*  qb     = (bf16*)(ws +  5774336);      //  3,145,728  z=1
  bf16*  vT     = (bf16*)(ws +  8920064);      //  3,145,728  z=2 [b][h*64+d][j]
  bf16*  rproj  = (bf16*)(ws + 12065792);      //  3,145,728 slot (768 rows used) z=3
  bf16*  attn_o = (bf16*)(ws + 15211520);      //  3,145,728
  float* uk     = (float*)(ws + 18357248);     //     98,304
  float* rd     = (float*)(ws + 18455552);     //     24,576   total ~18.5 MB
  (void)ws_size;

  const bf16* Wfc = arena + 1051648;
  const bf16* bfc = arena + 1313792;
  const unsigned int* key_raw = (const unsigned int*)d_in[0];

  Ptrs ptrs;  // Wk,bk, Wq,bq, Wv,bv, Wr,br, u,v, Wf,bf
  ptrs.p[0] = d_in[5];  ptrs.p[1] = d_in[6];  ptrs.p[2]  = d_in[7];  ptrs.p[3]  = d_in[8];
  ptrs.p[4] = d_in[9];  ptrs.p[5] = d_in[10]; ptrs.p[6]  = d_in[11]; ptrs.p[7]  = d_in[12];
  ptrs.p[8] = d_in[13]; ptrs.p[9] = d_in[14]; ptrs.p[10] = d_in[15]; ptrs.p[11] = d_in[16];

  dim3 blk(256);
  // 1) weights-only cast
  cast_inputs<<<dim3((CAST_GROUPS + 255)/256), blk, 0, stream>>>(ptrs, key_raw, arena);
  // 2) k+uk, q, vT, rproj+rd — one batched dispatch; A-tensors read raw
  proj_gemm<<<dim3(8, 24, 4), blk, 0, stream>>>(
      d_in[0], d_in[1], d_in[2], d_in[4], arena, key_raw, kb, vT, uk, rd);
  // 3) fused attention v2
  attn_kernel<<<dim3(LL/16, NHH, BB), blk, 0, stream>>>(
      qb, kb, vT, rproj, uk, rd, (const unsigned int*)d_in[3], attn_o);
  // 4) final projection -> FP32 out (64-tile, 384 blocks)
  gemm_final<<<dim3(8, 48, 1), blk, 0, stream>>>(attn_o, Wfc, bfc, out);
}

// Round 15
// 158.108 us; speedup vs baseline: 1.0311x; 1.0311x over previous
//
#include <hip/hip_runtime.h>
#include <hip/hip_bf16.h>

typedef short v8s __attribute__((ext_vector_type(8)));
typedef float v4f __attribute__((ext_vector_type(4)));
typedef float float4v __attribute__((ext_vector_type(4)));
typedef unsigned short u16x4 __attribute__((ext_vector_type(4)));

#define BB 8
#define LL 384
#define HIDD 512
#define NHH 8
#define DHH 64
#define PP 768
#define BL (BB*LL)   // 3072

using bf16 = __hip_bfloat16;

__device__ __forceinline__ v8s ld8(const bf16* p){
  return *reinterpret_cast<const v8s*>(p);
}

// ---------------------------------------------------------------------------
// Cast all 16 float tensors into one packed bf16 arena; mode (fp32 vs bf16)
// detected per-block by wave 0 from 1 KB of key words (L2-hot).
// [R10+R14 lesson: a separate fully-vectorized cast kernel beats inline
// conversion in GEMM staging — even vectorized cvt in the staging path
// regressed. R12 configuration == session best.]
// ---------------------------------------------------------------------------
struct Ptrs { const void* p[16]; };

#define CAST_GROUPS 1606528   // total elements / 4

__global__ __launch_bounds__(256)
void cast_inputs(Ptrs ptrs, bf16* __restrict__ dst){
  __shared__ int smode;
  int tid = threadIdx.x;
  if (tid < 64){
    const unsigned int* key_raw = (const unsigned int*)ptrs.p[0];
    int huge = 0, zeros = 0;
    #pragma unroll
    for (int c = 0; c < 4; c++){
      unsigned int lo = key_raw[tid*4 + c] & 0xFFFFu;
      if (((lo >> 7) & 0xFF) >= 0x90u) huge++;
      if (lo == 0u) zeros++;
    }
    #pragma unroll
    for (int off = 32; off; off >>= 1){
      huge  += __shfl_xor(huge,  off);
      zeros += __shfl_xor(zeros, off);
    }
    if (tid == 0) smode = (huge > 8 || zeros > 200) ? 1 : 0;
  }
  __syncthreads();
  int mode = smode;

  const int start[17] = {0, 393216, 786432, 1179648, 1277952, 1343488, 1343616,
                         1409152, 1409280, 1474816, 1474944, 1540480, 1540608,
                         1540736, 1540864, 1606400, 1606528};
  int g = blockIdx.x*256 + tid;
  if (g >= CAST_GROUPS) return;
  int s = 0;
  #pragma unroll
  for (int i = 0; i < 16; i++) if (g >= start[i+1]) s = i+1;
  int local = g - start[s];
  u16x4 outv;
  if (mode){
    const float4v* src = (const float4v*)ptrs.p[s];
    float4v f = src[local];
    #pragma unroll
    for (int i = 0; i < 4; i++){
      bf16 h = __float2bfloat16(f[i]);
      outv[i] = *reinterpret_cast<unsigned short*>(&h);
    }
  } else {
    const u16x4* src = (const u16x4*)ptrs.p[s];
    outv = src[local];
  }
  *reinterpret_cast<u16x4*>(dst + (long)g*4) = outv;
}

__global__ void zero_out(float* __restrict__ out, int n){
  int i = blockIdx.x*256 + threadIdx.x;
  if (i < n) out[i] = 0.f;
}

// ---------------------------------------------------------------------------
// Batched projection GEMM, LDS-staged: 128x64 tile, BK=64 (R9-proven).
//   z=0: kb + uk epilogue   z=1: qb   z=2: vT (transposed)   z=3: rproj + rd
// ---------------------------------------------------------------------------
__global__ __launch_bounds__(256)
void proj_gemm(const bf16* __restrict__ arena, bf16* __restrict__ outbase,
               bf16* __restrict__ vT, float* __restrict__ uk, float* __restrict__ rd)
{
  __shared__ alignas(16) bf16 ldsA[128*72];   // 18,432 B
  __shared__ alignas(16) bf16 ldsB[64*72];    //  9,216 B
  __shared__ float part[4*128];

  int z = blockIdx.z;
  if (z == 3 && blockIdx.y >= 6) return;
  const bf16* A    = arena + (long)z*1572864;
  const bf16* Bw   = arena + 5111808 + (long)z*262656;
  const bf16* bias = arena + 5373952 + (long)z*262656;

  int tid  = threadIdx.x;
  int lane = tid & 63, w = tid >> 6;
  int l16  = lane & 15, quad = lane >> 4;
  long g0  = (long)blockIdx.y * 128;
  int h    = blockIdx.x;
  int mloc = (w >> 1) * 64;
  int nloc = (w & 1) * 32;

  v4f acc[4][2] = {};
  for (int kk = 0; kk < HIDD; kk += 64){
    __syncthreads();
    #pragma unroll
    for (int c4 = 0; c4 < 4; c4++){
      int id = tid + c4*256;
      int row = id >> 3, c = id & 7;
      v8s v = ld8(A + (g0 + row)*HIDD + kk + c*8);
      *(v8s*)&ldsA[row*72 + c*8] = v;
    }
    #pragma unroll
    for (int c2 = 0; c2 < 2; c2++){
      int id = tid + c2*256;
      int row = id >> 3, c = id & 7;
      v8s v = ld8(Bw + (long)(h*64 + row)*HIDD + kk + c*8);
      *(v8s*)&ldsB[row*72 + c*8] = v;
    }
    __syncthreads();
    #pragma unroll
    for (int kq = 0; kq < 2; kq++){
      v8s af[4], bfr[2];
      #pragma unroll
      for (int ti = 0; ti < 4; ti++)
        af[ti] = *(const v8s*)&ldsA[(mloc + ti*16 + l16)*72 + kq*32 + quad*8];
      #pragma unroll
      for (int tj = 0; tj < 2; tj++)
        bfr[tj] = *(const v8s*)&ldsB[(nloc + tj*16 + l16)*72 + kq*32 + quad*8];
      #pragma unroll
      for (int ti = 0; ti < 4; ti++)
        #pragma unroll
        for (int tj = 0; tj < 2; tj++)
          acc[ti][tj] = __builtin_amdgcn_mfma_f32_16x16x32_bf16(af[ti], bfr[tj], acc[ti][tj], 0,0,0);
    }
  }

  // direct store (kb / qb / rproj) — C/D: col=l16, row=quad*4+r [m89/m91]
  if (z != 2){
    bf16* C = outbase + (long)z*1572864;
    #pragma unroll
    for (int ti = 0; ti < 4; ti++)
      #pragma unroll
      for (int tj = 0; tj < 2; tj++){
        int col = h*64 + nloc + tj*16 + l16;
        float bv = __bfloat162float(bias[col]);
        #pragma unroll
        for (int r = 0; r < 4; r++){
          long row = g0 + mloc + ti*16 + quad*4 + r;
          C[row*HIDD + col] = __float2bfloat16(acc[ti][tj][r] + bv);
        }
      }
  }

  // transposed-tile epilogues (vT / uk / rd)
  if (z != 1){
    __syncthreads();
    bf16* tileT = ldsA;                    // [64 cols][132 rows]
    #pragma unroll
    for (int ti = 0; ti < 4; ti++)
      #pragma unroll
      for (int tj = 0; tj < 2; tj++){
        int lcol = nloc + tj*16 + l16;
        float bv = __bfloat162float(bias[h*64 + lcol]);
        #pragma unroll
        for (int r = 0; r < 4; r++){
          int lrow = mloc + ti*16 + quad*4 + r;
          tileT[lcol*132 + lrow] = __float2bfloat16(acc[ti][tj][r] + bv);
        }
      }
    __syncthreads();

    if (z == 2){
      int b = (int)(g0/LL), j0 = (int)(g0%LL);
      int d = tid >> 2, jc = (tid & 3)*32;
      #pragma unroll
      for (int s = 0; s < 4; s++){
        v8s v = *(const v8s*)&tileT[d*132 + jc + s*8];
        *(v8s*)&vT[((long)b*HIDD + h*64 + d)*LL + j0 + jc + s*8] = v;
      }
    } else {
      const bf16* vec = arena + (z == 0 ? 6162432 : 6162944) + h*64;
      int row2 = tid & 63;
      int pi   = tid >> 6;
      float s0 = 0.f, s1 = 0.f;
      #pragma unroll
      for (int dd = 0; dd < 16; dd++){
        int d = pi*16 + dd;
        float uvd = __bfloat162float(vec[d]);
        s0 += __bfloat162float(tileT[d*132 + row2])      * uvd;
        s1 += __bfloat162float(tileT[d*132 + row2 + 64]) * uvd;
      }
      part[pi*128 + row2]      = s0;
      part[pi*128 + row2 + 64] = s1;
      __syncthreads();
      if (tid < 128){
        float tot = part[tid] + part[128+tid] + part[256+tid] + part[384+tid];
        if (z == 0){
          int b = (int)(g0/LL), j0 = (int)(g0%LL);
          uk[((long)b*NHH + h)*LL + j0 + tid] = tot;
        } else {
          rd[h*PP + (int)g0 + tid] = tot;
        }
      }
    }
  }
}

// ---------------------------------------------------------------------------
// Final projection GEMM (fp32 out), LDS-staged 128x64. Grid (8, 24).
// ---------------------------------------------------------------------------
__global__ __launch_bounds__(256)
void gemm_final(const bf16* __restrict__ A, const bf16* __restrict__ Bw,
                const bf16* __restrict__ bias, float* __restrict__ C)
{
  __shared__ alignas(16) bf16 ldsA[128*72];
  __shared__ alignas(16) bf16 ldsB[64*72];

  int tid  = threadIdx.x;
  int lane = tid & 63, w = tid >> 6;
  int l16  = lane & 15, quad = lane >> 4;
  long g0  = (long)blockIdx.y * 128;
  int h    = blockIdx.x;
  int mloc = (w >> 1) * 64;
  int nloc = (w & 1) * 32;

  v4f acc[4][2] = {};
  for (int kk = 0; kk < HIDD; kk += 64){
    __syncthreads();
    #pragma unroll
    for (int c4 = 0; c4 < 4; c4++){
      int id = tid + c4*256;
      int row = id >> 3, c = id & 7;
      v8s v = ld8(A + (g0 + row)*HIDD + kk + c*8);
      *(v8s*)&ldsA[row*72 + c*8] = v;
    }
    #pragma unroll
    for (int c2 = 0; c2 < 2; c2++){
      int id = tid + c2*256;
      int row = id >> 3, c = id & 7;
      v8s v = ld8(Bw + (long)(h*64 + row)*HIDD + kk + c*8);
      *(v8s*)&ldsB[row*72 + c*8] = v;
    }
    __syncthreads();
    #pragma unroll
    for (int kq = 0; kq < 2; kq++){
      v8s af[4], bfr[2];
      #pragma unroll
      for (int ti = 0; ti < 4; ti++)
        af[ti] = *(const v8s*)&ldsA[(mloc + ti*16 + l16)*72 + kq*32 + quad*8];
      #pragma unroll
      for (int tj = 0; tj < 2; tj++)
        bfr[tj] = *(const v8s*)&ldsB[(nloc + tj*16 + l16)*72 + kq*32 + quad*8];
      #pragma unroll
      for (int ti = 0; ti < 4; ti++)
        #pragma unroll
        for (int tj = 0; tj < 2; tj++)
          acc[ti][tj] = __builtin_amdgcn_mfma_f32_16x16x32_bf16(af[ti], bfr[tj], acc[ti][tj], 0,0,0);
    }
  }

  #pragma unroll
  for (int ti = 0; ti < 4; ti++)
    #pragma unroll
    for (int tj = 0; tj < 2; tj++){
      int col = h*64 + nloc + tj*16 + l16;
      float bv = __bfloat162float(bias[col]);
      #pragma unroll
      for (int r = 0; r < 4; r++){
        long row = g0 + mloc + ti*16 + quad*4 + r;
        C[row*HIDD + col] = acc[ti][tj][r] + bv;
      }
    }
}

// ---------------------------------------------------------------------------
// Fused attention v2 (R12-proven): register scores, quad-shuffle softmax,
// 26.5 KB LDS -> 6 blocks/CU, whole grid resident.
// ---------------------------------------------------------------------------
#define BTS_S 404
#define PB_S  408

__global__ __launch_bounds__(256, 6)
void attn_kernel(const bf16* __restrict__ qb, const bf16* __restrict__ kb,
                 const bf16* __restrict__ vT, const bf16* __restrict__ rproj,
                 const float* __restrict__ uk, const float* __restrict__ rd,
                 const unsigned int* __restrict__ sraw, bf16* __restrict__ attn_out)
{
  __shared__ alignas(16) bf16 Bts[16*BTS_S];  // 12,928 B
  __shared__ alignas(16) bf16 Pb[16*PB_S];    // 13,056 B
  __shared__ float wmax[4*16];
  __shared__ float wsum[4*16];
  __shared__ int s_slen;

  int i0 = blockIdx.x*16;
  int h  = blockIdx.y, b = blockIdx.z;
  int lane = threadIdx.x & 63, wave = threadIdx.x >> 6;
  int l16 = lane & 15, quad = lane >> 4;
  int p0 = 369 - i0;               // window start; in [1, 369]

  if (threadIdx.x == 0){
    bool i64 = true;
    for (int bb = 0; bb < BB; bb++){
      unsigned int w0 = sraw[2*bb], w1 = sraw[2*bb+1];
      if (!(w1 == 0u && w0 >= 1u && w0 < 100000u)) { i64 = false; break; }
    }
    unsigned int w = i64 ? sraw[2*b] : sraw[b];
    int v = (w < 100000u) ? (int)w : (int)(__uint_as_float(w) + 0.5f);
    s_slen = min(max(v, 0), LL);
  }

  const bf16* qp = qb + (long)(b*LL + i0 + l16)*HIDD + h*DHH;
  v8s aq0 = ld8(qp + quad*8);
  v8s aq1 = ld8(qp + 32 + quad*8);

  // Phase 0: Bts[i-i0][x] = q.rproj[p0+x] + rd[p0+x]
  #pragma unroll 2
  for (int nt = wave; nt < 25; nt += 4){
    int pbase = p0 + nt*16;
    int prow = min(pbase + l16, PP-1);
    const bf16* rp = rproj + (long)prow*HIDD + h*DHH;
    v8s b0 = ld8(rp + quad*8);
    v8s b1 = ld8(rp + 32 + quad*8);
    v4f acc = {};
    acc = __builtin_amdgcn_mfma_f32_16x16x32_bf16(aq0, b0, acc, 0,0,0);
    acc = __builtin_amdgcn_mfma_f32_16x16x32_bf16(aq1, b1, acc, 0,0,0);
    float rdv = rd[h*PP + prow];
    #pragma unroll
    for (int r = 0; r < 4; r++)
      Bts[(quad*4 + r)*BTS_S + nt*16 + l16] = __float2bfloat16(acc[r] + rdv);
  }
  __syncthreads();
  int slen = s_slen;

  // Phase 1: scores in registers; wave handles j-tiles wave+4t.
  float sv[6][4];
  #pragma unroll
  for (int t = 0; t < 6; t++){
    int j0 = (wave + 4*t)*16;
    const bf16* kp = kb + (long)(b*LL + j0 + l16)*HIDD + h*DHH;
    v8s b0 = ld8(kp + quad*8);
    v8s b1 = ld8(kp + 32 + quad*8);
    v4f acc = {};
    acc = __builtin_amdgcn_mfma_f32_16x16x32_bf16(aq0, b0, acc, 0,0,0);
    acc = __builtin_amdgcn_mfma_f32_16x16x32_bf16(aq1, b1, acc, 0,0,0);
    int j = j0 + l16;
    float c_add = uk[(b*NHH + h)*LL + j];
    #pragma unroll
    for (int r = 0; r < 4; r++){
      int il = quad*4 + r;
      float bt = __bfloat162float(Bts[il*BTS_S + (j - il + 15)]);
      float s = (acc[r] + bt + c_add) * 0.125f;
      sv[t][r] = (j >= slen) ? -1e15f : s;
    }
  }

  // Softmax across quad lanes + waves
  float mx[4];
  #pragma unroll
  for (int r = 0; r < 4; r++){
    float m = sv[0][r];
    #pragma unroll
    for (int t = 1; t < 6; t++) m = fmaxf(m, sv[t][r]);
    #pragma unroll
    for (int off = 1; off < 16; off <<= 1) m = fmaxf(m, __shfl_xor(m, off));
    mx[r] = m;
  }
  if (l16 == 0){
    #pragma unroll
    for (int r = 0; r < 4; r++) wmax[wave*16 + quad*4 + r] = mx[r];
  }
  __syncthreads();

  float gm[4];
  #pragma unroll
  for (int r = 0; r < 4; r++){
    int row = quad*4 + r;
    gm[r] = fmaxf(fmaxf(wmax[row], wmax[16+row]), fmaxf(wmax[32+row], wmax[48+row]));
  }
  float sm[4] = {0.f, 0.f, 0.f, 0.f};
  #pragma unroll
  for (int t = 0; t < 6; t++){
    int j = (wave + 4*t)*16 + l16;
    #pragma unroll
    for (int r = 0; r < 4; r++){
      float e = __expf(sv[t][r] - gm[r]);
      sm[r] += e;
      Pb[(quad*4 + r)*PB_S + j] = __float2bfloat16(e);
    }
  }
  #pragma unroll
  for (int r = 0; r < 4; r++){
    #pragma unroll
    for (int off = 1; off < 16; off <<= 1) sm[r] += __shfl_xor(sm[r], off);
  }
  if (l16 == 0){
    #pragma unroll
    for (int r = 0; r < 4; r++) wsum[wave*16 + quad*4 + r] = sm[r];
  }
  __syncthreads();

  float rsum_r[4];
  #pragma unroll
  for (int r = 0; r < 4; r++){
    int row = quad*4 + r;
    rsum_r[r] = wsum[row] + wsum[16+row] + wsum[32+row] + wsum[48+row];
  }

  // Phase 3: O = P @ v
  {
    int d0 = wave*16;
    v4f o = {};
    const bf16* vp = vT + ((long)(b*NHH + h)*DHH + d0 + l16)*LL;
    #pragma unroll 4
    for (int kt = 0; kt < 12; kt++){
      v8s a  = *reinterpret_cast<const v8s*>(&Pb[l16*PB_S + kt*32 + quad*8]);
      v8s bb = ld8(vp + kt*32 + quad*8);
      o = __builtin_amdgcn_mfma_f32_16x16x32_bf16(a, bb, o, 0,0,0);
    }
    #pragma unroll
    for (int r = 0; r < 4; r++){
      float val = o[r] / rsum_r[r];
      attn_out[(long)(b*LL + i0 + quad*4 + r)*HIDD + h*DHH + d0 + l16] = __float2bfloat16(val);
    }
  }
}

// ---------------------------------------------------------------------------
extern "C" void kernel_launch(void* const* d_in, const int* in_sizes, int n_in,
                              void* d_out, int out_size, void* d_ws, size_t ws_size,
                              hipStream_t stream)
{
  float* out = (float*)d_out;   // reference output dtype = float32

  const int expect[17] = {1572864, 1572864, 1572864, 8, 393216,
                          262144, 512, 262144, 512, 262144, 512, 262144, 512,
                          512, 512, 262144, 512};
  bool ok = (n_in == 17);
  if (ok) for (int i = 0; i < 17; i++) if (in_sizes[i] != expect[i]) { ok = false; break; }
  if (!ok){
    zero_out<<<dim3((out_size + 255)/256), dim3(256), 0, stream>>>(out, out_size);
    return;
  }

  char* ws = (char*)d_ws;
  bf16*  cast   = (bf16*)(ws);                 // 12,852,224 B packed arena
  bf16*  kb     = (bf16*)(ws + 12852224);      //  3,145,728  proj z=0
  bf16*  qb     = (bf16*)(ws + 15997952);      //  3,145,728  z=1
  bf16*  vT     = (bf16*)(ws + 19143680);      //  3,145,728  z=2 [b][h*64+d][j]
  bf16*  rproj  = (bf16*)(ws + 22289408);      //  3,145,728 slot (768 rows used) z=3
  bf16*  attn_o = (bf16*)(ws + 25435136);      //  3,145,728
  float* uk     = (float*)(ws + 28580864);     //     98,304
  float* rd     = (float*)(ws + 28679168);     //     24,576   total ~28.7 MB
  (void)ws_size;

  const bf16* Wfc = cast + 6163456;
  const bf16* bfc = cast + 6425600;

  Ptrs ptrs;
  {
    int k = 0;
    for (int i = 0; i < 17; i++){ if (i == 3) continue; ptrs.p[k++] = d_in[i]; }
  }

  dim3 blk(256);
  // 1) cast (mode detection fused in)
  cast_inputs<<<dim3((CAST_GROUPS + 255)/256), blk, 0, stream>>>(ptrs, cast);
  // 2) k+uk, q, vT, rproj+rd — one batched LDS-staged dispatch
  proj_gemm<<<dim3(8, 24, 4), blk, 0, stream>>>(cast, kb, vT, uk, rd);
  // 3) fused attention v2 (register softmax, 6 blocks/CU)
  attn_kernel<<<dim3(LL/16, NHH, BB), blk, 0, stream>>>(
      qb, kb, vT, rproj, uk, rd, (const unsigned int*)d_in[3], attn_o);
  // 4) final projection -> FP32 out (LDS-staged 128-tile)
  gemm_final<<<dim3(8, 24, 1), blk, 0, stream>>>(attn_o, Wfc, bfc, out);
}